// Round 3
// baseline (248.312 us; speedup 1.0000x reference)
//
#include <hip/hip_runtime.h>

// LIF neuron forward: T=8 timesteps, x shape [T*B, C, H, W] = [256,128,32,32] f32.
// Recurrence per spatial element (independent across B,C,H,W):
//   mem = beta*mem + (1-beta)*x_t ; spike = (mem >= 0.3*Vth)*Vth ;
//   mem -= spike ; out_t = spike/0.05
//
// R1 -> R2: loads/stores were interleaved per-t by the compiler (VGPR=20),
// and vmcnt counts stores too -- every load-wait drained the previous store,
// serializing ~8 store latencies (87 us vs ~43 us roofline). Now: issue all 8
// loads, fence with sched_barrier, compute in place, then store all 8 at the
// end (nontemporal -- output is write-once, keep x resident in L3).
// R2 -> R3: __builtin_nontemporal_store rejects HIP_vector_type<float,4>;
// use a native clang ext_vector_type(4) float vector instead (same layout,
// still dwordx4 loads/stores).
//
// Bit-exactness notes (decisions flip 0<->20, zero flips allowed):
//  - beta = f32(exp(f32(-0.05))) = 0x1.E7078Cp-1 (correctly rounded; verified
//    absmax 0.0 in R1).
//  - mem update uses __fmul_rn/__fadd_rn to forbid FMA contraction (numpy
//    evaluates beta*mem and (1-beta)*xt as separate rn-multiplies + rn-add).
//  - (1.0f - beta) exact; Vth clamp round-trips to 1.0f; vth/0.05f == 20.0f.

#define T_STEPS 8
#define S_ELEMS (32 * 128 * 32 * 32)   // per-timestep elements = 4,194,304
#define S4 (S_ELEMS / 4)               // float4 per timestep = 1,048,576
#define BLOCK 256

typedef float f32x4 __attribute__((ext_vector_type(4)));

__global__ __launch_bounds__(BLOCK) void lif_fwd_kernel(
    const f32x4* __restrict__ x, const float* __restrict__ vth_ptr,
    f32x4* __restrict__ out) {
  const int i = blockIdx.x * BLOCK + threadIdx.x;  // float4 column index

  // Vth clamp (no-grad): relu(Vth - 5e-4) + 5e-4, all f32 rn. (scalar path)
  const float vth_raw = vth_ptr[0];
  const float vth = __fadd_rn(fmaxf(__fsub_rn(vth_raw, 0.0005f), 0.0f), 0.0005f);
  const float thr = __fmul_rn(0.3f, vth);      // ALPHA * Vth
  const float outval = __fdiv_rn(vth, 0.05f);  // Vth / DELTA_T (== 20.0f)

  const float beta = 0x1.E7078Cp-1f;        // f32(exp(f32(-0.05)))
  const float omb = __fsub_rn(1.0f, beta);  // exact

  // --- Phase 1: issue ALL 8 loads before any store exists in the stream. ---
  f32x4 xs[T_STEPS];
#pragma unroll
  for (int t = 0; t < T_STEPS; ++t) xs[t] = x[i + (size_t)t * S4];
  __builtin_amdgcn_sched_barrier(0);  // keep loads hoisted above everything below

  // --- Phase 2: recurrence, overwriting xs[t] with the output tile. ---
  float m0 = 0.f, m1 = 0.f, m2 = 0.f, m3 = 0.f;
#pragma unroll
  for (int t = 0; t < T_STEPS; ++t) {
    m0 = __fadd_rn(__fmul_rn(beta, m0), __fmul_rn(omb, xs[t].x));
    m1 = __fadd_rn(__fmul_rn(beta, m1), __fmul_rn(omb, xs[t].y));
    m2 = __fadd_rn(__fmul_rn(beta, m2), __fmul_rn(omb, xs[t].z));
    m3 = __fadd_rn(__fmul_rn(beta, m3), __fmul_rn(omb, xs[t].w));
    const bool s0 = (m0 >= thr), s1 = (m1 >= thr), s2 = (m2 >= thr),
               s3 = (m3 >= thr);
    f32x4 o;
    o.x = s0 ? outval : 0.0f;
    o.y = s1 ? outval : 0.0f;
    o.z = s2 ? outval : 0.0f;
    o.w = s3 ? outval : 0.0f;
    if (s0) m0 = __fsub_rn(m0, vth);
    if (s1) m1 = __fsub_rn(m1, vth);
    if (s2) m2 = __fsub_rn(m2, vth);
    if (s3) m3 = __fsub_rn(m3, vth);
    xs[t] = o;
  }
  __builtin_amdgcn_sched_barrier(0);  // no store drifts up between loads/compute

  // --- Phase 3: stream all 8 stores; nontemporal (write-once, never re-read;
  // keeps x from being evicted from the 256 MB L3 by our own writes). ---
#pragma unroll
  for (int t = 0; t < T_STEPS; ++t)
    __builtin_nontemporal_store(xs[t], &out[i + (size_t)t * S4]);
}

extern "C" void kernel_launch(void* const* d_in, const int* in_sizes, int n_in,
                              void* d_out, int out_size, void* d_ws,
                              size_t ws_size, hipStream_t stream) {
  const f32x4* x = (const f32x4*)d_in[0];
  const float* vth = (const float*)d_in[1];
  f32x4* out = (f32x4*)d_out;
  // S4 float4 columns / 256 threads = 4096 blocks (16 per CU).
  lif_fwd_kernel<<<S4 / BLOCK, BLOCK, 0, stream>>>(x, vth, out);
}

// Round 4
// 240.339 us; speedup vs baseline: 1.0332x; 1.0332x over previous
//
#include <hip/hip_runtime.h>

// LIF neuron forward: T=8 timesteps, x shape [T*B, C, H, W] = [256,128,32,32] f32.
// Recurrence per spatial element (independent across B,C,H,W):
//   mem = beta*mem + (1-beta)*x_t ; spike = (mem >= 0.3*Vth)*Vth ;
//   mem -= spike ; out_t = spike/0.05
//
// History:
//  R1: compiler interleaved load/compute/store per t (VGPR=20) -> 87 us,
//      ~2 TB/s, all pipes idle. Exposed-latency, not BW.
//  R3: tried phases via sched_barrier(0) + nt stores. sched_barrier is only a
//      MachineScheduler region boundary -- IR passes sank the loads anyway
//      (VGPR=24 proves xs[8] never lived as 32 regs). nt stores regressed
//      87->100 us. FETCH unchanged at 64 MB.
//  R4: force phases with asm volatile memory clobber (loads can't sink past,
//      stores can't hoist above). No nt. Single change axis. Tell: VGPR>=44.
//
// Bit-exactness notes (decisions flip 0<->20, zero flips allowed):
//  - beta = f32(exp(f32(-0.05))) = 0x1.E7078Cp-1 (correctly rounded; verified
//    absmax 0.0 in R1/R3).
//  - mem update uses __fmul_rn/__fadd_rn to forbid FMA contraction (numpy
//    evaluates beta*mem and (1-beta)*xt as separate rn-multiplies + rn-add).
//  - (1.0f - beta) exact; Vth clamp round-trips to 1.0f; vth/0.05f == 20.0f.

#define T_STEPS 8
#define S_ELEMS (32 * 128 * 32 * 32)   // per-timestep elements = 4,194,304
#define S4 (S_ELEMS / 4)               // float4 per timestep = 1,048,576
#define BLOCK 256

typedef float f32x4 __attribute__((ext_vector_type(4)));

__global__ __launch_bounds__(BLOCK) void lif_fwd_kernel(
    const f32x4* __restrict__ x, const float* __restrict__ vth_ptr,
    f32x4* __restrict__ out) {
  const int i = blockIdx.x * BLOCK + threadIdx.x;  // float4 column index

  // Vth clamp (no-grad): relu(Vth - 5e-4) + 5e-4, all f32 rn. (scalar path)
  const float vth_raw = vth_ptr[0];
  const float vth = __fadd_rn(fmaxf(__fsub_rn(vth_raw, 0.0005f), 0.0f), 0.0005f);
  const float thr = __fmul_rn(0.3f, vth);      // ALPHA * Vth
  const float outval = __fdiv_rn(vth, 0.05f);  // Vth / DELTA_T (== 20.0f)

  const float beta = 0x1.E7078Cp-1f;        // f32(exp(f32(-0.05)))
  const float omb = __fsub_rn(1.0f, beta);  // exact

  // --- Phase 1: issue ALL 8 loads (8 KB/wave in flight, MLP=8). ---
  f32x4 xs[T_STEPS];
#pragma unroll
  for (int t = 0; t < T_STEPS; ++t) xs[t] = x[i + (size_t)t * S4];

  // Full compiler memory barrier: loads above cannot sink below this (the asm
  // may write the memory they read); stores below cannot hoist above it.
  asm volatile("" ::: "memory");

  // --- Phase 2: recurrence, overwriting xs[t] with the output tile
  // (in-place keeps live set at 32 data VGPRs). ---
  float m0 = 0.f, m1 = 0.f, m2 = 0.f, m3 = 0.f;
#pragma unroll
  for (int t = 0; t < T_STEPS; ++t) {
    m0 = __fadd_rn(__fmul_rn(beta, m0), __fmul_rn(omb, xs[t].x));
    m1 = __fadd_rn(__fmul_rn(beta, m1), __fmul_rn(omb, xs[t].y));
    m2 = __fadd_rn(__fmul_rn(beta, m2), __fmul_rn(omb, xs[t].z));
    m3 = __fadd_rn(__fmul_rn(beta, m3), __fmul_rn(omb, xs[t].w));
    const bool s0 = (m0 >= thr), s1 = (m1 >= thr), s2 = (m2 >= thr),
               s3 = (m3 >= thr);
    f32x4 o;
    o.x = s0 ? outval : 0.0f;
    o.y = s1 ? outval : 0.0f;
    o.z = s2 ? outval : 0.0f;
    o.w = s3 ? outval : 0.0f;
    if (s0) m0 = __fsub_rn(m0, vth);
    if (s1) m1 = __fsub_rn(m1, vth);
    if (s2) m2 = __fsub_rn(m2, vth);
    if (s3) m3 = __fsub_rn(m3, vth);
    xs[t] = o;
  }

  asm volatile("" ::: "memory");

  // --- Phase 3: stream all 8 stores (plain; nt regressed in R3). ---
#pragma unroll
  for (int t = 0; t < T_STEPS; ++t) out[i + (size_t)t * S4] = xs[t];
}

extern "C" void kernel_launch(void* const* d_in, const int* in_sizes, int n_in,
                              void* d_out, int out_size, void* d_ws,
                              size_t ws_size, hipStream_t stream) {
  const f32x4* x = (const f32x4*)d_in[0];
  const float* vth = (const float*)d_in[1];
  f32x4* out = (f32x4*)d_out;
  // S4 float4 columns / 256 threads = 4096 blocks (16 per CU).
  lif_fwd_kernel<<<S4 / BLOCK, BLOCK, 0, stream>>>(x, vth, out);
}

// Round 5
// 236.081 us; speedup vs baseline: 1.0518x; 1.0180x over previous
//
#include <hip/hip_runtime.h>

// LIF neuron forward: T=8 timesteps, x shape [T*B, C, H, W] = [256,128,32,32] f32.
// Recurrence per spatial element (independent across B,C,H,W):
//   mem = beta*mem + (1-beta)*x_t ; spike = (mem >= 0.3*Vth)*Vth ;
//   mem -= spike ; out_t = spike/0.05
//
// History:
//  R1: compiler interleaved load/compute/store per t (VGPR=20) -> 87 us,
//      ~2.3 TB/s HBM, all pipes idle. Exposed-latency suspected.
//  R3: sched_barrier(0) phases + nt stores. sched_barrier is only a MIR
//      scheduling boundary -- IR sank the loads anyway (VGPR=24). nt stores
//      regressed to 100 us. Reverted nt.
//  R4: asm volatile memory clobber. Defeated too: x/out are __restrict__, so
//      AA proves the clobber can't alias them and sinks the loads past it
//      (VGPR still 24, dur still 87 us).
//  R5: pin by DATAFLOW -- one volatile asm with all 8 xs[] as tied "+v"
//      operands between loads and compute. Compute reads the asm's outputs,
//      so all 8 loads must issue+complete first. Restrict is irrelevant to a
//      data dependence. Tell: VGPR >= 40.
//
// Bit-exactness notes (decisions flip 0<->20, zero flips allowed):
//  - beta = f32(exp(f32(-0.05))) = 0x1.E7078Cp-1 (correctly rounded; verified
//    absmax 0.0 in R1/R3/R4).
//  - mem update uses __fmul_rn/__fadd_rn to forbid FMA contraction (numpy
//    evaluates beta*mem and (1-beta)*xt as separate rn-multiplies + rn-add).
//  - (1.0f - beta) exact; Vth clamp round-trips to 1.0f; vth/0.05f == 20.0f.

#define T_STEPS 8
#define S_ELEMS (32 * 128 * 32 * 32)   // per-timestep elements = 4,194,304
#define S4 (S_ELEMS / 4)               // float4 per timestep = 1,048,576
#define BLOCK 256

typedef float f32x4 __attribute__((ext_vector_type(4)));

__global__ __launch_bounds__(BLOCK) void lif_fwd_kernel(
    const f32x4* __restrict__ x, const float* __restrict__ vth_ptr,
    f32x4* __restrict__ out) {
  const int i = blockIdx.x * BLOCK + threadIdx.x;  // float4 column index

  // Vth clamp (no-grad): relu(Vth - 5e-4) + 5e-4, all f32 rn. (scalar path)
  const float vth_raw = vth_ptr[0];
  const float vth = __fadd_rn(fmaxf(__fsub_rn(vth_raw, 0.0005f), 0.0f), 0.0005f);
  const float thr = __fmul_rn(0.3f, vth);      // ALPHA * Vth
  const float outval = __fdiv_rn(vth, 0.05f);  // Vth / DELTA_T (== 20.0f)

  const float beta = 0x1.E7078Cp-1f;        // f32(exp(f32(-0.05)))
  const float omb = __fsub_rn(1.0f, beta);  // exact

  // --- Phase 1: issue ALL 8 loads (8 KB/wave in flight, MLP=8). ---
  f32x4 xs[T_STEPS];
#pragma unroll
  for (int t = 0; t < T_STEPS; ++t) xs[t] = x[i + (size_t)t * S4];

  // Dataflow pin: every xs[t] is an output of this asm, so all 8 loads must
  // issue AND complete (vmcnt(0)) before anything below can start. Alias
  // analysis cannot break a register data dependence.
  asm volatile(""
               : "+v"(xs[0]), "+v"(xs[1]), "+v"(xs[2]), "+v"(xs[3]),
                 "+v"(xs[4]), "+v"(xs[5]), "+v"(xs[6]), "+v"(xs[7]));

  // --- Phase 2: recurrence, overwriting xs[t] with the output tile
  // (in-place keeps live set at 32 data VGPRs). Stores may interleave here;
  // that's fine -- all loads are already done. ---
  float m0 = 0.f, m1 = 0.f, m2 = 0.f, m3 = 0.f;
#pragma unroll
  for (int t = 0; t < T_STEPS; ++t) {
    m0 = __fadd_rn(__fmul_rn(beta, m0), __fmul_rn(omb, xs[t].x));
    m1 = __fadd_rn(__fmul_rn(beta, m1), __fmul_rn(omb, xs[t].y));
    m2 = __fadd_rn(__fmul_rn(beta, m2), __fmul_rn(omb, xs[t].z));
    m3 = __fadd_rn(__fmul_rn(beta, m3), __fmul_rn(omb, xs[t].w));
    const bool s0 = (m0 >= thr), s1 = (m1 >= thr), s2 = (m2 >= thr),
               s3 = (m3 >= thr);
    f32x4 o;
    o.x = s0 ? outval : 0.0f;
    o.y = s1 ? outval : 0.0f;
    o.z = s2 ? outval : 0.0f;
    o.w = s3 ? outval : 0.0f;
    if (s0) m0 = __fsub_rn(m0, vth);
    if (s1) m1 = __fsub_rn(m1, vth);
    if (s2) m2 = __fsub_rn(m2, vth);
    if (s3) m3 = __fsub_rn(m3, vth);
    out[i + (size_t)t * S4] = o;
  }
}

extern "C" void kernel_launch(void* const* d_in, const int* in_sizes, int n_in,
                              void* d_out, int out_size, void* d_ws,
                              size_t ws_size, hipStream_t stream) {
  const f32x4* x = (const f32x4*)d_in[0];
  const float* vth = (const float*)d_in[1];
  f32x4* out = (f32x4*)d_out;
  // S4 float4 columns / 256 threads = 4096 blocks (16 per CU).
  lif_fwd_kernel<<<S4 / BLOCK, BLOCK, 0, stream>>>(x, vth, out);
}